// Round 14
// baseline (96.644 us; speedup 1.0000x reference)
//
#include <hip/hip_runtime.h>
#include <math.h>

static constexpr int H = 512, W = 512, NPTS = 19, BATCH = 4;
static constexpr int HW = H * W;
static constexpr int NPLANES = BATCH * NPTS;                 // 76
static constexpr long long TOTAL = (long long)NPLANES * HW;  // 19,922,944 per channel group
static constexpr float INV_OFF = 1.0f / 40.0f;

static constexpr int BLOCKSX = 32;                    // 32*76 = 2432 main blocks
static constexpr int SITER   = (HW / 4) / (BLOCKSX * 256);   // 8 float4 steps/thread
static constexpr int DEPTH   = 4;                     // ring slots
static constexpr int NSLOTS  = BLOCKSX * NPLANES;     // 2432 float4 partials (39 KB)
static constexpr unsigned int NBLOCKS = BLOCKSX * NPLANES;   // 2432

// ws layout: [0 .. NSLOTS*4) floats = partials; at byte NSLOTS*16: u32 ticket
// (zeroed per launch via hipMemsetAsync — capture-safe).
//
// Single-dispatch structure: main blocks (bn < 76) run the R13 hot loop
// unchanged and release their partial with store + threadfence + ticket
// increment. One extra grid row (bn == 76, bx == 0) runs a __noinline__
// spin-waiter that polls the ticket at agent scope, acquire-fences, reduces
// the partials in f64 and writes out[0]. The finalize body is cold and
// never inlined, so the hot path's regalloc is not perturbed (R4/R9 lesson:
// inlined atomic finalize collapsed the load pipeline).
__device__ __noinline__ void homl_finalize(
    const float* __restrict__ ws_, float* __restrict__ out,
    unsigned int* ticket)
{
    if (threadIdx.x == 0) {
        while (__hip_atomic_load(ticket, __ATOMIC_RELAXED,
                                 __HIP_MEMORY_SCOPE_AGENT) < NBLOCKS)
            __builtin_amdgcn_s_sleep(2);
    }
    __syncthreads();
    __builtin_amdgcn_fence(__ATOMIC_ACQUIRE, "agent");   // invalidate stale L1/L2

    double bs = 0.0, xs = 0.0, ys = 0.0, c = 0.0;
    for (int i = threadIdx.x; i < NSLOTS; i += 256) {
        const float4 p = *reinterpret_cast<const float4*>(ws_ + (size_t)i * 4);
        bs += (double)p.x; xs += (double)p.y; ys += (double)p.z; c += (double)p.w;
    }
    #pragma unroll
    for (int off = 32; off > 0; off >>= 1) {
        bs += __shfl_down(bs, off);
        xs += __shfl_down(xs, off);
        ys += __shfl_down(ys, off);
        c  += __shfl_down(c, off);
    }
    __shared__ double sd[4][4];
    const int wave = threadIdx.x >> 6;
    const int lane = threadIdx.x & 63;
    if (lane == 0) { sd[0][wave] = bs; sd[1][wave] = xs; sd[2][wave] = ys; sd[3][wave] = c; }
    __syncthreads();
    if (threadIdx.x == 0) {
        double tb = 0.0, txs = 0.0, tys = 0.0, tc = 0.0;
        #pragma unroll
        for (int wv = 0; wv < 4; ++wv) {
            tb += sd[0][wv]; txs += sd[1][wv]; tys += sd[2][wv]; tc += sd[3][wv];
        }
        const double bce_mean = tb / (double)TOTAL;
        out[0] = (float)(2.0 * bce_mean + txs / tc + tys / tc);
    }
}

__global__ __launch_bounds__(256) void homl_all(
    const float* __restrict__ fm, const int* __restrict__ lm,
    float* __restrict__ ws_, float* __restrict__ out)
{
    const int bn = blockIdx.y;             // 0..76 (76 = waiter row)
    const int bx = blockIdx.x;             // 0..31
    unsigned int* ticket = reinterpret_cast<unsigned int*>(ws_ + (size_t)NSLOTS * 4);

    if (bn == NPLANES) {                   // waiter row: only bx==0 works
        if (bx == 0) homl_finalize(ws_, out, ticket);
        return;
    }

    const int b  = bn / NPTS;
    const int n  = bn % NPTS;

    const float* ph_base = fm + ((size_t)b * 3 * NPTS + n) * HW;
    const float* px_base = ph_base + (size_t)NPTS * HW;
    const float* py_base = px_base + (size_t)NPTS * HW;

    // ---- issue bulk ring loads FIRST (landmark-independent) ----
    // Block chunk = 8192 floats (32KB); step chunk = 1024 floats.
    const int tbase = bx * (SITER * 1024) + (int)threadIdx.x * 4;  // float index
    float4 buf[DEPTH];
    #pragma unroll
    for (int s0 = 0; s0 < DEPTH - 1; ++s0)
        buf[s0] = *reinterpret_cast<const float4*>(ph_base + tbase + s0 * 1024);
    __builtin_amdgcn_sched_barrier(0);     // keep ring issue ahead of prelude

    // ---- landmark + disk prelude (scattered loads land under bulk) ----
    int x = lm[bn * 2 + 0];
    int y = lm[bn * 2 + 1];
    x = min(max(x, 1), W - 1);             // clamp_landmarks
    y = min(max(y, 1), H - 1);

    // Box rows for this block: brow = bx + 32*rr, rr = 0..nrows-1 (81 rows total).
    const int nrows = (bx < 17) ? 3 : 2;
    float phv, pxv, pyv, txv, tyv;
    bool  val;
    {
        const int idx = threadIdx.x;               // need < nrows*81 (<= 243)
        const int rr  = idx / 81;
        const int cc  = idx - rr * 81;
        const int brow = bx + 32 * rr;             // 0..80
        const int dy  = brow - 40;                 // r - y
        const int dx  = cc - 40;                   // c - x
        const int r   = y + dy;
        const int c   = x + dx;
        val = (rr < nrows) && (r >= 0) && (r < H) &&
              (c >= 0) && (c < W) && (dy * dy + dx * dx <= 1600);
        const size_t off = val ? ((size_t)r * W + c) : 0;   // branchless safe addr
        phv = ph_base[off];
        pxv = px_base[off];
        pyv = py_base[off];
        txv = (float)(-dy) * INV_OFF;              // (y - r)/40
        tyv = (float)(-dx) * INV_OFF;              // (x - c)/40
    }

    // ---- bulk: pure-stream softplus, 8 steps x 1 float4/thread, 4-slot ring ----
    float bce_l = 0.0f;                    // sum of log2(prod(1+e)); *ln2 at the end
    #pragma unroll
    for (int s = 0; s < SITER; ++s) {
        if (s + DEPTH - 1 < SITER)             // prefetch 3 steps ahead
            buf[(s + DEPTH - 1) & (DEPTH - 1)] = *reinterpret_cast<const float4*>(
                ph_base + tbase + (s + DEPTH - 1) * 1024);

        const float4 q = buf[s & (DEPTH - 1)];
        // e_k = 2^(ph*lg e); m = (1+e0)(1+e1)(1+e2)(1+e3); one log2 per 4 elems
        const float e0 = __builtin_amdgcn_exp2f(1.44269504089f * q.x);
        const float e1 = __builtin_amdgcn_exp2f(1.44269504089f * q.y);
        const float e2 = __builtin_amdgcn_exp2f(1.44269504089f * q.z);
        const float e3 = __builtin_amdgcn_exp2f(1.44269504089f * q.w);
        float m = 1.0f + e0;
        m = fmaf(e1, m, m);
        m = fmaf(e2, m, m);
        m = fmaf(e3, m, m);
        bce_l += __builtin_amdgcn_logf(m);     // v_log_f32 == log2
    }

    // ---- combine: bce = ln2 * sum(log2) - sum_disk ph; disk L1 terms ----
    float bce = 0.69314718056f * bce_l;
    float lxs = 0.0f, lys = 0.0f, cntf = 0.0f;
    if (val) {
        bce -= phv;
        lxs  = fabsf(pxv - txv);
        lys  = fabsf(pyv - tyv);
        cntf = 1.0f;
    }

    // ---- joint reduction: wave shuffle, then cross-wave via LDS ----
    #pragma unroll
    for (int off = 32; off > 0; off >>= 1) {
        bce  += __shfl_down(bce, off);
        lxs  += __shfl_down(lxs, off);
        lys  += __shfl_down(lys, off);
        cntf += __shfl_down(cntf, off);
    }

    __shared__ float redf[4][4];
    const int wave = threadIdx.x >> 6;
    const int lane = threadIdx.x & 63;
    if (lane == 0) {
        redf[0][wave] = bce; redf[1][wave] = lxs;
        redf[2][wave] = lys; redf[3][wave] = cntf;
    }
    __syncthreads();
    __builtin_amdgcn_sched_barrier(0);     // wall: keep epilogue out of loop scheduling
    if (threadIdx.x == 0) {
        float fb = 0.0f, fx = 0.0f, fy = 0.0f, fc = 0.0f;
        #pragma unroll
        for (int wv = 0; wv < 4; ++wv) {
            fb += redf[0][wv];
            fx += redf[1][wv];
            fy += redf[2][wv];
            fc += redf[3][wv];
        }
        float4 o; o.x = fb; o.y = fx; o.z = fy; o.w = fc;
        *reinterpret_cast<float4*>(ws_ + (size_t)(bn * BLOCKSX + bx) * 4) = o;
        __threadfence();                   // release partial to agent scope
        atomicAdd(ticket, 1u);
    }
}

extern "C" void kernel_launch(void* const* d_in, const int* in_sizes, int n_in,
                              void* d_out, int out_size, void* d_ws, size_t ws_size,
                              hipStream_t stream) {
    const float* fm  = (const float*)d_in[0];
    const int*   lm  = (const int*)d_in[1];
    float*       out = (float*)d_out;
    float*       ws  = (float*)d_ws;    // needs NSLOTS*16 + 4 = 38,916 B

    // zero the ticket only (partials are all overwritten before being read)
    hipMemsetAsync((char*)d_ws + (size_t)NSLOTS * 16, 0, 4, stream);

    dim3 grid(BLOCKSX, NPLANES + 1);    // 32 x 77; row 76 = waiter (bx>0 exit)
    homl_all<<<grid, 256, 0, stream>>>(fm, lm, ws, out);
}

// Round 15
// 22.760 us; speedup vs baseline: 4.2463x; 4.2463x over previous
//
#include <hip/hip_runtime.h>
#include <math.h>

static constexpr int H = 512, W = 512, NPTS = 19, BATCH = 4;
static constexpr int HW = H * W;
static constexpr int NPLANES = BATCH * NPTS;                 // 76
static constexpr long long TOTAL = (long long)NPLANES * HW;  // 19,922,944 per channel group
static constexpr float INV_OFF = 1.0f / 40.0f;

static constexpr int BLOCKSX = 32;                    // 32*76 = 2432 blocks
static constexpr int SITER   = (HW / 4) / (BLOCKSX * 256);   // 8 float4 steps/thread
static constexpr int DEPTH   = 4;                     // ring slots
static constexpr int NSLOTS  = BLOCKSX * NPLANES;     // 2432 float4 partials (39 KB)

// R13 state (best verified: 23.0 us). Identity:
// sum[max(ph,0) - ph*th + log1p(e^-|ph|)] = sum softplus(ph) - sum_disk ph.
// Bulk loop is landmark-free streaming softplus with logs chained 4:1;
// ring loads issued BEFORE the landmark-dependent prelude (sched_barrier
// pinned). Two-kernel structure is FINAL: single-dispatch fusion via any
// device-scope atomic/fence collapses the load-pipeline codegen (VGPR->20,
// ~7x regression) — proven three ways in R4 (inline f64 atomics), R9
// (inline ticket), R14 (__noinline__ spin-waiter + release fence).
__global__ __launch_bounds__(256) void homl_main(
    const float* __restrict__ fm, const int* __restrict__ lm,
    float* __restrict__ ws_)
{
    const int bn = blockIdx.y;             // 0..75
    const int bx = blockIdx.x;             // 0..31
    const int b  = bn / NPTS;
    const int n  = bn % NPTS;

    const float* ph_base = fm + ((size_t)b * 3 * NPTS + n) * HW;
    const float* px_base = ph_base + (size_t)NPTS * HW;
    const float* py_base = px_base + (size_t)NPTS * HW;

    // ---- issue bulk ring loads FIRST (landmark-independent) ----
    // Block chunk = 8192 floats (32KB); step chunk = 1024 floats.
    const int tbase = bx * (SITER * 1024) + (int)threadIdx.x * 4;  // float index
    float4 buf[DEPTH];
    #pragma unroll
    for (int s0 = 0; s0 < DEPTH - 1; ++s0)
        buf[s0] = *reinterpret_cast<const float4*>(ph_base + tbase + s0 * 1024);
    __builtin_amdgcn_sched_barrier(0);     // keep ring issue ahead of prelude

    // ---- landmark + disk prelude (scattered loads land under bulk) ----
    int x = lm[bn * 2 + 0];
    int y = lm[bn * 2 + 1];
    x = min(max(x, 1), W - 1);             // clamp_landmarks
    y = min(max(y, 1), H - 1);

    // Box rows for this block: brow = bx + 32*rr, rr = 0..nrows-1 (81 rows total).
    const int nrows = (bx < 17) ? 3 : 2;
    float phv, pxv, pyv, txv, tyv;
    bool  val;
    {
        const int idx = threadIdx.x;               // need < nrows*81 (<= 243)
        const int rr  = idx / 81;
        const int cc  = idx - rr * 81;
        const int brow = bx + 32 * rr;             // 0..80
        const int dy  = brow - 40;                 // r - y
        const int dx  = cc - 40;                   // c - x
        const int r   = y + dy;
        const int c   = x + dx;
        val = (rr < nrows) && (r >= 0) && (r < H) &&
              (c >= 0) && (c < W) && (dy * dy + dx * dx <= 1600);
        const size_t off = val ? ((size_t)r * W + c) : 0;   // branchless safe addr
        phv = ph_base[off];
        pxv = px_base[off];
        pyv = py_base[off];
        txv = (float)(-dy) * INV_OFF;              // (y - r)/40
        tyv = (float)(-dx) * INV_OFF;              // (x - c)/40
    }

    // ---- bulk: pure-stream softplus, 8 steps x 1 float4/thread, 4-slot ring ----
    float bce_l = 0.0f;                    // sum of log2(prod(1+e)); *ln2 at the end
    #pragma unroll
    for (int s = 0; s < SITER; ++s) {
        if (s + DEPTH - 1 < SITER)             // prefetch 3 steps ahead
            buf[(s + DEPTH - 1) & (DEPTH - 1)] = *reinterpret_cast<const float4*>(
                ph_base + tbase + (s + DEPTH - 1) * 1024);

        const float4 q = buf[s & (DEPTH - 1)];
        // e_k = 2^(ph*lg e); m = (1+e0)(1+e1)(1+e2)(1+e3); one log2 per 4 elems
        const float e0 = __builtin_amdgcn_exp2f(1.44269504089f * q.x);
        const float e1 = __builtin_amdgcn_exp2f(1.44269504089f * q.y);
        const float e2 = __builtin_amdgcn_exp2f(1.44269504089f * q.z);
        const float e3 = __builtin_amdgcn_exp2f(1.44269504089f * q.w);
        float m = 1.0f + e0;
        m = fmaf(e1, m, m);
        m = fmaf(e2, m, m);
        m = fmaf(e3, m, m);
        bce_l += __builtin_amdgcn_logf(m);     // v_log_f32 == log2
    }

    // ---- combine: bce = ln2 * sum(log2) - sum_disk ph; disk L1 terms ----
    float bce = 0.69314718056f * bce_l;
    float lxs = 0.0f, lys = 0.0f, cntf = 0.0f;
    if (val) {
        bce -= phv;
        lxs  = fabsf(pxv - txv);
        lys  = fabsf(pyv - tyv);
        cntf = 1.0f;
    }

    // ---- joint reduction: wave shuffle, then cross-wave via LDS ----
    #pragma unroll
    for (int off = 32; off > 0; off >>= 1) {
        bce  += __shfl_down(bce, off);
        lxs  += __shfl_down(lxs, off);
        lys  += __shfl_down(lys, off);
        cntf += __shfl_down(cntf, off);
    }

    __shared__ float redf[4][4];
    const int wave = threadIdx.x >> 6;
    const int lane = threadIdx.x & 63;
    if (lane == 0) {
        redf[0][wave] = bce; redf[1][wave] = lxs;
        redf[2][wave] = lys; redf[3][wave] = cntf;
    }
    __syncthreads();
    if (threadIdx.x == 0) {
        float fb = 0.0f, fx = 0.0f, fy = 0.0f, fc = 0.0f;
        #pragma unroll
        for (int wv = 0; wv < 4; ++wv) {
            fb += redf[0][wv];
            fx += redf[1][wv];
            fy += redf[2][wv];
            fc += redf[3][wv];
        }
        float4 o; o.x = fb; o.y = fx; o.z = fy; o.w = fc;
        *reinterpret_cast<float4*>(ws_ + (size_t)(bn * BLOCKSX + bx) * 4) = o;
    }
}

// 1024 threads: <=3 independent float4 loads per thread (one latency round),
// f64 accumulate, 16-wave LDS reduce.
__global__ __launch_bounds__(1024) void homl_final(
    const float* __restrict__ ws_, float* __restrict__ out)
{
    double bs = 0.0, xs = 0.0, ys = 0.0, c = 0.0;
    for (int i = threadIdx.x; i < NSLOTS; i += 1024) {
        const float4 p = *reinterpret_cast<const float4*>(ws_ + (size_t)i * 4);
        bs += (double)p.x; xs += (double)p.y; ys += (double)p.z; c += (double)p.w;
    }
    #pragma unroll
    for (int off = 32; off > 0; off >>= 1) {
        bs += __shfl_down(bs, off);
        xs += __shfl_down(xs, off);
        ys += __shfl_down(ys, off);
        c  += __shfl_down(c, off);
    }
    __shared__ double sd[4][16];
    const int wave = threadIdx.x >> 6;
    const int lane = threadIdx.x & 63;
    if (lane == 0) { sd[0][wave] = bs; sd[1][wave] = xs; sd[2][wave] = ys; sd[3][wave] = c; }
    __syncthreads();
    if (threadIdx.x == 0) {
        double tb = 0.0, txs = 0.0, tys = 0.0, tc = 0.0;
        #pragma unroll
        for (int wv = 0; wv < 16; ++wv) {
            tb += sd[0][wv]; txs += sd[1][wv]; tys += sd[2][wv]; tc += sd[3][wv];
        }
        const double bce_mean = tb / (double)TOTAL;
        out[0] = (float)(2.0 * bce_mean + txs / tc + tys / tc);
    }
}

extern "C" void kernel_launch(void* const* d_in, const int* in_sizes, int n_in,
                              void* d_out, int out_size, void* d_ws, size_t ws_size,
                              hipStream_t stream) {
    const float* fm  = (const float*)d_in[0];
    const int*   lm  = (const int*)d_in[1];
    float*       out = (float*)d_out;
    float*       ws  = (float*)d_ws;    // needs 2432 * 16 = 38,912 B

    dim3 grid(BLOCKSX, NPLANES);        // 32 x 76 = 2432 uniform blocks
    homl_main<<<grid, 256, 0, stream>>>(fm, lm, ws);
    homl_final<<<1, 1024, 0, stream>>>(ws, out);
}